// Round 10
// baseline (221.075 us; speedup 1.0000x reference)
//
#include <hip/hip_runtime.h>
#include <hip/hip_bf16.h>

using bf16 = __hip_bfloat16;
typedef __attribute__((ext_vector_type(8))) short short8x;            // 8 bf16 (4 VGPRs)
typedef __attribute__((ext_vector_type(4))) float f32x4;              // MFMA accumulator

__device__ __forceinline__ float b2f(bf16 x) { return __bfloat162float(x); }
__device__ __forceinline__ bf16  f2b(float x) { return __float2bfloat16(x); }
__device__ __forceinline__ short bbits(float x) { bf16 b = f2b(x); short s; __builtin_memcpy(&s, &b, 2); return s; }
__device__ __forceinline__ float bu2f(unsigned short s) {
    unsigned v = ((unsigned)s) << 16; float f; __builtin_memcpy(&f, &v, 4); return f;
}
// flag-dispatched input load: f32==1 -> fp32 storage, else bf16 storage
__device__ __forceinline__ float ldin(const void* p, int i, int f32) {
    return f32 ? ((const float*)p)[i] : b2f(((const bf16*)p)[i]);
}

// cheap exact-gelu: A&S 7.1.26 erf (abs err 1.5e-7), branchless
__device__ __forceinline__ float gelu_f(float x) {
    const float z = fabsf(x) * 0.70710678118654752f;
    const float t = __builtin_amdgcn_rcpf(1.0f + 0.3275911f * z);
    const float poly = t * (0.254829592f + t * (-0.284496736f +
                       t * (1.421413741f + t * (-1.453152027f + t * 1.061405429f))));
    const float erfv = 1.0f - poly * __expf(-z * z);
    return 0.5f * x * (1.0f + copysignf(erfv, x));
}

// problem dims (fixed by setup_inputs)
#define TI 6
#define HI 40
#define WI 40
#define TO 12
#define HO 80
#define WO 80
#define NIN (TI*HI*WI)    // 9600
#define NOUT (TO*HO*WO)   // 76800

// ---------------- workspace layout ----------------
#define F_B1    0                       // [256] effective bias (pw1_b + pw1·dw1_b + rel_cell)
#define F_ACO   (F_B1 + 256)            // [6][256] rel-coord coefficients
#define F_SC    (F_ACO + 6*256)         // [3][NIN] shortcut conv output
#define F_DT    (F_SC + 3*NIN)          // [2][TO] signed d (t axis)
#define F_DH    (F_DT + 2*TO)           // [2][HO]
#define F_DW    (F_DH + 2*HO)           // [2][WO]
#define F_FT    (F_DW + 2*WO)           // [TO] trilinear frac
#define F_FH    (F_FT + TO)             // [HO]
#define F_FW    (F_FH + HO)             // [WO]
#define F_FC1B  (F_FW + WO)             // [256] fc1 bias
#define F_FC2W  (F_FC1B + 256)          // [3*256] fc2 weights
#define F_FC2B  (F_FC2W + 768)          // [3] fc2 bias (pad 4)
#define F_END   (F_FC2B + 4)
#define I_IT    0
#define I_IH    (I_IT + 2*TO)
#define I_IW    (I_IH + 2*HO)
#define I_LT0   (I_IW + 2*WO)
#define I_LT1   (I_LT0 + TO)
#define I_LH0   (I_LT1 + TO)
#define I_LH1   (I_LH0 + HO)
#define I_LW0   (I_LH1 + HO)
#define I_LW1   (I_LW0 + WO)
#define I_FLAG  (I_LW1 + WO)
#define I_END   (I_FLAG + 1)

#define MPOS 64     // positions per k_main block (4 M-tiles)
#define CSTR 72     // per-corner stride in u (shorts): 144 B, 16B-aligned
#define USTR 584    // u row stride: 292 words = 4 mod 32 -> 2-way max banks
#define ZPAD 264    // z row stride: 132 words = 4 mod 32 -> 2-way max banks

// per-axis tables, replicating reference `near` (eps=1e-6, round-half-even) and `lin_idx`
__device__ __forceinline__ void axis_tables(int i, int n_out, int n_in,
                                            float* dvals, int* ivals,
                                            int* l0, int* l1, float* fr) {
    const float r_out = 1.0f / (float)n_out;
    const float r_in  = 1.0f / (float)n_in;
    const float c = -1.0f + r_out + 2.0f * r_out * (float)i;
    #pragma unroll
    for (int v = 0; v < 2; ++v) {
        const float vv = v ? 1.0f : -1.0f;
        float cc = c + vv * r_in + 1e-6f;
        cc = fminf(fmaxf(cc, -1.0f + 1e-6f), 1.0f - 1e-6f);
        float fx = rintf(((cc + 1.0f) * (float)n_in - 1.0f) * 0.5f);
        fx = fminf(fmaxf(fx, 0.0f), (float)(n_in - 1));
        const int idx = (int)fx;
        const float l = -1.0f + r_in + 2.0f * r_in * (float)idx;
        dvals[v * n_out + i] = (c - l) * (float)n_in;
        ivals[v * n_out + i] = idx;
    }
    float x = fminf(fmaxf(((c + 1.0f) * (float)n_in - 1.0f) * 0.5f, 0.0f), (float)(n_in - 1));
    const float x0 = floorf(x);
    fr[i] = x - x0;
    const int i0 = (int)x0;
    l0[i] = i0;
    l1[i] = min(i0 + 1, n_in - 1);
}

// ---------------- kernel A: flat setup (263 blocks, shallow coalesced duties) ----------------
__global__ __launch_bounds__(256)
void k_setup(const void* __restrict__ feat,
             const void* __restrict__ dw1_w, const void* __restrict__ dw1_b,
             const void* __restrict__ pw1_w, const void* __restrict__ pw1_b,
             const void* __restrict__ fc1_w, const void* __restrict__ fc1_b,
             const void* __restrict__ fc2_w, const void* __restrict__ fc2_b,
             const void* __restrict__ sc_dw_w, const void* __restrict__ sc_dw_b,
             const void* __restrict__ sc_pw_w, const void* __restrict__ sc_pw_b,
             bf16* __restrict__ featT, bf16* __restrict__ fc1P,
             bf16* __restrict__ W1fP, float* __restrict__ F, int* __restrict__ I) {
    const int tid = threadIdx.x;
    const int b = blockIdx.x;
    __shared__ int sflag;
    // per-block dtype detection (wave-0 ballot): even halfwords of fp32 data
    // are mantissa junk (~15% in bf16-exponent window); of bf16 data ~100%.
    if (tid < 64) {
        const unsigned short* u = (const unsigned short*)feat;
        const unsigned e = (u[2 * tid] >> 7) & 0xFFu;
        const unsigned long long m = __ballot(e >= 0x68u && e <= 0x8Eu);
        if (tid == 0) sflag = (__popcll(m) < 32) ? 1 : 0;
    }
    __syncthreads();
    const int f32 = sflag;

    if (b < 150) {
        // ---- featT transpose + shortcut; 64 positions ----
        const int pos0 = b * 64;
        __shared__ float tF[64][66];
        __shared__ float scw_l[3][64];
        __shared__ float scb_l[4];
        {
            const int p = tid & 63, cg = tid >> 6;
            #pragma unroll
            for (int cc = 0; cc < 16; ++cc) {
                const int c = cg * 16 + cc;
                tF[c][p] = ldin(feat, c * NIN + pos0 + p, f32);
            }
        }
        if (tid < 192)
            scw_l[tid >> 6][tid & 63] = ldin(sc_pw_w, tid, f32) * ldin(sc_dw_w, tid & 63, f32);
        if (tid < 3) {
            float sb = ldin(sc_pw_b, tid, f32);
            for (int c = 0; c < 64; ++c)
                sb += ldin(sc_pw_w, tid * 64 + c, f32) * ldin(sc_dw_b, c, f32);
            scb_l[tid] = sb;
        }
        __syncthreads();
        #pragma unroll
        for (int it = 0; it < 2; ++it) {
            const int id = it * 256 + tid;          // 0..511
            const int p = id >> 3, c8 = id & 7;
            bf16 v[8];
            #pragma unroll
            for (int jj = 0; jj < 8; ++jj) v[jj] = f2b(tF[c8 * 8 + jj][p]);
            *(short8x*)&featT[(size_t)(pos0 + p) * 64 + c8 * 8] = *(short8x*)v;
        }
        if (tid < 192) {
            const int j = tid >> 6, p = tid & 63;
            float s = scb_l[j];
            for (int c = 0; c < 64; ++c) s += tF[c][p] * scw_l[j][c];
            F[F_SC + j * NIN + pos0 + p] = s;
        }
        return;
    }
    if (b < 214) {
        // ---- W1fP pack: g in [0,16384), one fragment per thread ----
        const int g = (b - 150) * 256 + tid;
        const int kc = g >> 10, nt = (g >> 6) & 15, wl = g & 63;
        const int n = nt * 16 + (wl & 15);
        const int K0 = kc * 32 + (wl >> 4) * 8;
        bf16 v[8];
        #pragma unroll
        for (int jj = 0; jj < 8; ++jj) {
            const int ch = 24 + K0 + jj;
            v[jj] = f2b(ldin(pw1_w, n * 539 + ch, f32) * ldin(dw1_w, ch, f32));
        }
        *(short8x*)&W1fP[(size_t)g * 8] = *(short8x*)v;
        return;
    }
    if (b < 246) {
        // ---- fc1P pack: g in [0,8192), one fragment per thread ----
        const int g = (b - 214) * 256 + tid;
        const int kc = g >> 10, nt = (g >> 6) & 15, wl = g & 63;
        const int n = nt * 16 + (wl & 15);
        const int K0 = kc * 32 + (wl >> 4) * 8;
        bf16 v[8];
        #pragma unroll
        for (int jj = 0; jj < 8; ++jj) v[jj] = f2b(ldin(fc1_w, n * 256 + K0 + jj, f32));
        *(short8x*)&fc1P[(size_t)g * 8] = *(short8x*)v;
        return;
    }
    if (b < 262) {
        // ---- B1 + ACO fold: channels n = (b-246)*16 + r ----
        const int r = tid >> 4, part = tid & 15;
        const int n = (b - 246) * 16 + r;
        float s = 0.f;
        for (int ch = part; ch < 539; ch += 16)
            s += ldin(pw1_w, n * 539 + ch, f32) * ldin(dw1_b, ch, f32);
        #pragma unroll
        for (int m = 1; m <= 8; m <<= 1) s += __shfl_xor(s, m, 64);
        if (part == 0) {
            float bacc = ldin(pw1_b, n, f32) + s;
            #pragma unroll
            for (int ch = 536; ch < 539; ++ch)
                bacc += 2.0f * ldin(pw1_w, n * 539 + ch, f32) * ldin(dw1_w, ch, f32);
            F[F_B1 + n] = bacc;
            float A[6] = {0.f, 0.f, 0.f, 0.f, 0.f, 0.f};
            #pragma unroll
            for (int k = 0; k < 8; ++k) {
                A[(k >> 2)]           += ldin(pw1_w, n*539 + 3*k + 0, f32) * ldin(dw1_w, 3*k + 0, f32);
                A[2 + ((k >> 1) & 1)] += ldin(pw1_w, n*539 + 3*k + 1, f32) * ldin(dw1_w, 3*k + 1, f32);
                A[4 + (k & 1)]        += ldin(pw1_w, n*539 + 3*k + 2, f32) * ldin(dw1_w, 3*k + 2, f32);
            }
            #pragma unroll
            for (int i = 0; i < 6; ++i) F[F_ACO + i * 256 + n] = A[i];
        }
        return;
    }
    // ---- block 262: flag + tables + small staging ----
    if (tid == 0) I[I_FLAG] = f32;
    F[F_FC1B + tid] = ldin(fc1_b, tid, f32);
    for (int r = tid; r < 768; r += 256) F[F_FC2W + r] = ldin(fc2_w, r, f32);
    if (tid < 3) F[F_FC2B + tid] = ldin(fc2_b, tid, f32);
    if (tid < TO) axis_tables(tid, TO, TI, F + F_DT, I + I_IT, I + I_LT0, I + I_LT1, F + F_FT);
    if (tid < HO) axis_tables(tid, HO, HI, F + F_DH, I + I_IH, I + I_LH0, I + I_LH1, F + F_FH);
    if (tid < WO) axis_tables(tid, WO, WI, F + F_DW, I + I_IW, I + I_LW0, I + I_LW1, F + F_FW);
}

// ---------------- kernel B: fused main, 64 positions/block (4 M-tiles) ----------------
__global__ __launch_bounds__(256)
void k_main(const bf16* __restrict__ featT, const bf16* __restrict__ fc1P,
            const bf16* __restrict__ W1fP, const float* __restrict__ F,
            const int* __restrict__ I, void* __restrict__ outv) {
    const int tid = threadIdx.x;
    const int pos0 = blockIdx.x * MPOS;
    const int f32 = I[I_FLAG];

    __shared__ __align__(16) short ubuf[MPOS * USTR];   // 74752 B; z[p][o] aliased inside later
    __shared__ float sh_dv[MPOS * 6];                   // 1536 B
    __shared__ float sh_g[3 * MPOS];                    // 768 B
    __shared__ __align__(16) int sh_scr[1024];          // 4096 B: ipos+wk, later redc
    int*   sh_ipos = sh_scr;                            // [p][8] ints (dead after stage 2)
    float* sh_wk   = (float*)(sh_scr + 512);            // [p][8] floats (dead after stage 2)
    float* redc    = (float*)sh_scr;                    // [p][4][3] floats (768) aliases both
    // total LDS = 81152 B -> 2 blocks/CU

    // ---- stage 1: per-position scalars (threads 0..63) ----
    if (tid < MPOS) {
        const int p = tid;
        const int pos = pos0 + p;
        const int t = pos / (HO * WO);
        const int rem = pos - t * (HO * WO);
        const int h = rem / WO;
        const int w = rem - h * WO;
        const int   iTa[2] = { I[I_IT + t], I[I_IT + TO + t] };
        const float dTv[2] = { F[F_DT + t], F[F_DT + TO + t] };
        const int   iHa[2] = { I[I_IH + h], I[I_IH + HO + h] };
        const float dHv[2] = { F[F_DH + h], F[F_DH + HO + h] };
        const int   iWa[2] = { I[I_IW + w], I[I_IW + WO + w] };
        const float dWv[2] = { F[F_DW + w], F[F_DW + WO + w] };
        sh_dv[p * 6 + 0] = dTv[0]; sh_dv[p * 6 + 1] = dTv[1];
        sh_dv[p * 6 + 2] = dHv[0]; sh_dv[p * 6 + 3] = dHv[1];
        sh_dv[p * 6 + 4] = dWv[0]; sh_dv[p * 6 + 5] = dWv[1];
        const float aT[2] = { fabsf(dTv[0]), fabsf(dTv[1]) };
        const float aH[2] = { fabsf(dHv[0]), fabsf(dHv[1]) };
        const float aW[2] = { fabsf(dWv[0]), fabsf(dWv[1]) };
        const float tot = (aT[0] + aT[1]) * (aH[0] + aH[1]) * (aW[0] + aW[1]) + 8e-9f;
        #pragma unroll
        for (int k = 0; k < 8; ++k) {
            const int at = k >> 2, ah = (k >> 1) & 1, aw = k & 1;
            sh_wk[p * 8 + k] = (aT[1 - at] * aH[1 - ah] * aW[1 - aw] + 1e-9f) / tot;
            sh_ipos[p * 8 + k] = iTa[at] * (HI * WI) + iHa[ah] * WI + iWa[aw];
        }
        // trilinear shortcut g
        const int a0 = I[I_LT0 + t], a1 = I[I_LT1 + t];
        const int bh0 = I[I_LH0 + h], bh1 = I[I_LH1 + h];
        const int c0 = I[I_LW0 + w], c1 = I[I_LW1 + w];
        const float fT = F[F_FT + t], fH = F[F_FH + h], fW = F[F_FW + w];
        #pragma unroll
        for (int jj = 0; jj < 3; ++jj) {
            const float* Sj = F + F_SC + jj * NIN;
            const int i0 = a0 * (HI * WI), i1 = a1 * (HI * WI);
            const float v000 = Sj[i0 + bh0 * WI + c0], v001 = Sj[i0 + bh0 * WI + c1];
            const float v010 = Sj[i0 + bh1 * WI + c0], v011 = Sj[i0 + bh1 * WI + c1];
            const float v100 = Sj[i1 + bh0 * WI + c0], v101 = Sj[i1 + bh0 * WI + c1];
            const float v110 = Sj[i1 + bh1 * WI + c0], v111 = Sj[i1 + bh1 * WI + c1];
            const float u00 = v000 * (1.f - fT) + v100 * fT;
            const float u01 = v001 * (1.f - fT) + v101 * fT;
            const float u10 = v010 * (1.f - fT) + v110 * fT;
            const float u11 = v011 * (1.f - fT) + v111 * fT;
            const float q0 = u00 * (1.f - fH) + u10 * fH;
            const float q1 = u01 * (1.f - fH) + u11 * fH;
            sh_g[jj * MPOS + p] = q0 * (1.f - fW) + q1 * fW;
        }
    }
    __syncthreads();

    // ---- stage 2: build u[p][k][c] = wk * featT[ipos[p][k]][c]  (bf16) ----
    {
        const int c8 = tid & 7;
        int pair = tid >> 3;                 // (p,k) pair index, +32 per iter; 512 pairs
        #pragma unroll
        for (int it = 0; it < 16; ++it, pair += 32) {
            const int p = pair >> 3, k = pair & 7;
            const int row = sh_ipos[p * 8 + k];
            const float wk = sh_wk[p * 8 + k];
            const short8x fr = *(const short8x*)(featT + (size_t)row * 64 + c8 * 8);
            short v[8];
            #pragma unroll
            for (int jj = 0; jj < 8; ++jj)
                v[jj] = bbits(wk * bu2f((unsigned short)fr[jj]));
            *(short8x*)&ubuf[p * USTR + k * CSTR + c8 * 8] = *(short8x*)v;
        }
    }
    __syncthreads();

    // ---- stage 3: z-GEMM (M=64,N=256,K=512) + bias/ACO epilogue -> z bf16 in ubuf ----
    const int wl = tid & 63, w = tid >> 6;
    const int col = wl & 15, quad = wl >> 4;
    {
        f32x4 zacc[4][4];
        #pragma unroll
        for (int mt = 0; mt < 4; ++mt)
            #pragma unroll
            for (int nt = 0; nt < 4; ++nt) zacc[mt][nt] = (f32x4){0.f, 0.f, 0.f, 0.f};
        const short8x* bp = (const short8x*)W1fP;
        #pragma unroll 2
        for (int kc = 0; kc < 16; ++kc) {
            const int corner = kc >> 1;
            const int cin = (kc & 1) * 32 + quad * 8;
            short8x a[4];
            #pragma unroll
            for (int mt = 0; mt < 4; ++mt)
                a[mt] = *(const short8x*)&ubuf[(col + mt * 16) * USTR + corner * CSTR + cin];
            #pragma unroll
            for (int nt = 0; nt < 4; ++nt) {
                const short8x bb = bp[((size_t)kc * 16 + w * 4 + nt) * 64 + wl];
                #pragma unroll
                for (int mt = 0; mt < 4; ++mt)
                    zacc[mt][nt] = __builtin_amdgcn_mfma_f32_16x16x32_bf16(a[mt], bb, zacc[mt][nt], 0, 0, 0);
            }
        }
        __syncthreads();   // all u reads complete before aliasing ubuf as z
        // epilogue: z = zacc + b1 + Acoef·dv; D layout m=quad*4+r (+16*mt), n=w*64+nt*16+col
        #pragma unroll
        for (int nt = 0; nt < 4; ++nt) {
            const int n = w * 64 + nt * 16 + col;
            const float b1 = F[F_B1 + n];
            float Ac[6];
            #pragma unroll
            for (int i = 0; i < 6; ++i) Ac[i] = F[F_ACO + i * 256 + n];
            #pragma unroll
            for (int mt = 0; mt < 4; ++mt)
                #pragma unroll
                for (int r = 0; r < 4; ++r) {
                    const int p = mt * 16 + quad * 4 + r;
                    float x = zacc[mt][nt][r] + b1;
                    #pragma unroll
                    for (int i = 0; i < 6; ++i) x += Ac[i] * sh_dv[p * 6 + i];
                    ubuf[p * ZPAD + n] = bbits(x);
                }
        }
    }
    __syncthreads();

    // ---- stage 4: fc1 via MFMA (4 M-tiles) + gelu + fc2 partials in-register ----
    {
        f32x4 acc[4][4];
        #pragma unroll
        for (int mt = 0; mt < 4; ++mt)
            #pragma unroll
            for (int nt = 0; nt < 4; ++nt) acc[mt][nt] = (f32x4){0.f, 0.f, 0.f, 0.f};
        const short8x* bp = (const short8x*)fc1P;
        #pragma unroll 2
        for (int kc = 0; kc < 8; ++kc) {
            short8x a[4];
            #pragma unroll
            for (int mt = 0; mt < 4; ++mt)
                a[mt] = *(const short8x*)&ubuf[(col + mt * 16) * ZPAD + kc * 32 + quad * 8];
            #pragma unroll
            for (int nt = 0; nt < 4; ++nt) {
                const short8x b = bp[((size_t)kc * 16 + w * 4 + nt) * 64 + wl];
                #pragma unroll
                for (int mt = 0; mt < 4; ++mt)
                    acc[mt][nt] = __builtin_amdgcn_mfma_f32_16x16x32_bf16(a[mt], b, acc[mt][nt], 0, 0, 0);
            }
        }
        float part[4][3][4];
        #pragma unroll
        for (int mt = 0; mt < 4; ++mt)
            #pragma unroll
            for (int jj = 0; jj < 3; ++jj)
                #pragma unroll
                for (int r = 0; r < 4; ++r) part[mt][jj][r] = 0.f;
        #pragma unroll
        for (int nt = 0; nt < 4; ++nt) {
            const int j = w * 64 + nt * 16 + col;
            const float fb = F[F_FC1B + j];
            const float w0 = F[F_FC2W + j];
            const float w1 = F[F_FC2W + 256 + j];
            const float w2 = F[F_FC2W + 512 + j];
            #pragma unroll
            for (int mt = 0; mt < 4; ++mt)
                #pragma unroll
                for (int r = 0; r < 4; ++r) {
                    const float hh = gelu_f(acc[mt][nt][r] + fb);
                    part[mt][0][r] += w0 * hh;
                    part[mt][1][r] += w1 * hh;
                    part[mt][2][r] += w2 * hh;
                }
        }
        // butterfly-reduce over the 16 col-lanes
        #pragma unroll
        for (int m = 1; m <= 8; m <<= 1)
            #pragma unroll
            for (int mt = 0; mt < 4; ++mt)
                #pragma unroll
                for (int jj = 0; jj < 3; ++jj)
                    #pragma unroll
                    for (int r = 0; r < 4; ++r)
                        part[mt][jj][r] += __shfl_xor(part[mt][jj][r], m, 64);
        __syncthreads();   // ipos/wk dead; safe to alias scratch as redc
        if (col == 0) {
            #pragma unroll
            for (int mt = 0; mt < 4; ++mt)
                #pragma unroll
                for (int jj = 0; jj < 3; ++jj)
                    #pragma unroll
                    for (int r = 0; r < 4; ++r) {
                        const int p = mt * 16 + quad * 4 + r;
                        redc[(p * 4 + w) * 3 + jj] = part[mt][jj][r];
                    }
        }
    }
    __syncthreads();

    // ---- stage 5: combine 4 wave-partials + shortcut + store ----
    if (tid < 192) {
        const int p = tid / 3, jj = tid - 3 * p;
        float a = F[F_FC2B + jj] + sh_g[jj * MPOS + p];
        #pragma unroll
        for (int w2 = 0; w2 < 4; ++w2) a += redc[(p * 4 + w2) * 3 + jj];
        const int oidx = jj * NOUT + pos0 + p;
        if (f32) ((float*)outv)[oidx] = a;
        else     ((bf16*)outv)[oidx] = f2b(a);
    }
}

extern "C" void kernel_launch(void* const* d_in, const int* in_sizes, int n_in,
                              void* d_out, int out_size, void* d_ws, size_t ws_size,
                              hipStream_t stream) {
    const void* feat    = d_in[0];
    const void* dw1_w   = d_in[1];
    const void* dw1_b   = d_in[2];
    const void* pw1_w   = d_in[3];
    const void* pw1_b   = d_in[4];
    const void* fc1_w   = d_in[5];
    const void* fc1_b   = d_in[6];
    const void* fc2_w   = d_in[7];
    const void* fc2_b   = d_in[8];
    const void* sc_dw_w = d_in[9];
    const void* sc_dw_b = d_in[10];
    const void* sc_pw_w = d_in[11];
    const void* sc_pw_b = d_in[12];

    const size_t FEATT_BYTES = (size_t)NIN * 64 * 2;      // 1,228,800
    const size_t FC1P_BYTES  = (size_t)256 * 256 * 2;     // 131,072
    const size_t W1FP_BYTES  = (size_t)512 * 256 * 2;     // 262,144
    bf16*  featT = (bf16*)d_ws;
    bf16*  fc1P  = (bf16*)((char*)d_ws + FEATT_BYTES);
    bf16*  W1fP  = (bf16*)((char*)d_ws + FEATT_BYTES + FC1P_BYTES);
    float* F     = (float*)((char*)d_ws + FEATT_BYTES + FC1P_BYTES + W1FP_BYTES);
    int*   I     = (int*)(F + F_END);
    // total ws need ~1.8 MB

    k_setup<<<263, 256, 0, stream>>>(feat, dw1_w, dw1_b, pw1_w, pw1_b, fc1_w, fc1_b,
                                     fc2_w, fc2_b, sc_dw_w, sc_dw_b, sc_pw_w, sc_pw_b,
                                     featT, fc1P, W1fP, F, I);
    k_main<<<NOUT / MPOS, 256, 0, stream>>>(featT, fc1P, W1fP, F, I, (void*)d_out);
}

// Round 11
// 175.403 us; speedup vs baseline: 1.2604x; 1.2604x over previous
//
#include <hip/hip_runtime.h>
#include <hip/hip_bf16.h>

using bf16 = __hip_bfloat16;
typedef __attribute__((ext_vector_type(8))) short short8x;             // 8 bf16 (4 VGPRs)
typedef __attribute__((ext_vector_type(8))) unsigned short ushort8x;   // 8 bf16 bits
typedef __attribute__((ext_vector_type(4))) float f32x4;               // MFMA accumulator

__device__ __forceinline__ float b2f(bf16 x) { return __bfloat162float(x); }
__device__ __forceinline__ bf16  f2b(float x) { return __float2bfloat16(x); }
__device__ __forceinline__ short bbits(float x) { bf16 b = f2b(x); short s; __builtin_memcpy(&s, &b, 2); return s; }
__device__ __forceinline__ float bu2f(unsigned short s) {
    unsigned v = ((unsigned)s) << 16; float f; __builtin_memcpy(&f, &v, 4); return f;
}
// flag-dispatched input load: f32==1 -> fp32 storage, else bf16 storage
__device__ __forceinline__ float ldin(const void* p, int i, int f32) {
    return f32 ? ((const float*)p)[i] : b2f(((const bf16*)p)[i]);
}

// cheap exact-gelu: A&S 7.1.26 erf (abs err ~1.5e-7), branchless
__device__ __forceinline__ float gelu_f(float x) {
    const float z = fabsf(x) * 0.70710678118654752f;
    const float t = __builtin_amdgcn_rcpf(1.0f + 0.3275911f * z);
    const float poly = t * (0.254829592f + t * (-0.284496736f +
                       t * (1.421413741f + t * (-1.453152027f + t * 1.061405429f))));
    const float erfv = 1.0f - poly * __expf(-z * z);
    return 0.5f * x * (1.0f + copysignf(erfv, x));
}

// problem dims (fixed by setup_inputs)
#define TI 6
#define HI 40
#define WI 40
#define TO 12
#define HO 80
#define WO 80
#define NIN (TI*HI*WI)    // 9600
#define NOUT (TO*HO*WO)   // 76800

// ---------------- workspace layout ----------------
// [0, P_BYTES)     : P bf16 [8][NIN][256]  (corner projections)
// [+FC1P_BYTES)    : fc1P bf16 [8 kc][16 nt][64 lane][8]  (fc1 B-fragments)
// [+W1FP_BYTES)    : W1fP bf16 [16 kcg][16 nt][64 lane][8]  (W1f B-fragments)
// float region F:
#define F_B1    0                       // [256] effective bias
#define F_ACO   (F_B1 + 256)            // [6][256] rel-coord coefficients
#define F_SCW   (F_ACO + 6*256)         // [3][64] sc_pw_w*sc_dw_w
#define F_SCB   (F_SCW + 3*64)          // [3] folded sc bias (pad 4)
#define F_SC    (F_SCB + 4)             // [3][NIN] shortcut conv output
#define F_DT    (F_SC + 3*NIN)          // [2][TO] signed d (t axis)
#define F_DH    (F_DT + 2*TO)           // [2][HO]
#define F_DW    (F_DH + 2*HO)           // [2][WO]
#define F_FT    (F_DW + 2*WO)           // [TO] trilinear frac
#define F_FH    (F_FT + TO)             // [HO]
#define F_FW    (F_FH + HO)             // [WO]
#define F_FC1B  (F_FW + WO)             // [256] fc1 bias
#define F_FC2W  (F_FC1B + 256)          // [3*256] fc2 weights
#define F_FC2B  (F_FC2W + 768)          // [3] fc2 bias (pad 4)
#define F_END   (F_FC2B + 4)
// int region I:
#define I_IT    0
#define I_IH    (I_IT + 2*TO)
#define I_IW    (I_IH + 2*HO)
#define I_LT0   (I_IW + 2*WO)
#define I_LT1   (I_LT0 + TO)
#define I_LH0   (I_LT1 + TO)
#define I_LH1   (I_LH0 + HO)
#define I_LW0   (I_LH1 + HO)
#define I_LW1   (I_LW0 + WO)
#define I_FLAG  (I_LW1 + WO)
#define I_END   (I_FLAG + 1)

#define MPOS 32     // positions per k_main block
#define ZPAD 264    // bf16 row stride (132 words = 4 mod 32 -> conflict-light)
#define FT_S 72     // bf16 row stride for feat tile in k_corner (36 words = 4 mod 32)

// per-axis tables, replicating reference `near` (eps=1e-6, round-half-even) and `lin_idx`
__device__ __forceinline__ void axis_tables(int i, int n_out, int n_in,
                                            float* dvals, int* ivals,
                                            int* l0, int* l1, float* fr) {
    const float r_out = 1.0f / (float)n_out;
    const float r_in  = 1.0f / (float)n_in;
    const float c = -1.0f + r_out + 2.0f * r_out * (float)i;
    #pragma unroll
    for (int v = 0; v < 2; ++v) {
        const float vv = v ? 1.0f : -1.0f;
        float cc = c + vv * r_in + 1e-6f;
        cc = fminf(fmaxf(cc, -1.0f + 1e-6f), 1.0f - 1e-6f);
        float fx = rintf(((cc + 1.0f) * (float)n_in - 1.0f) * 0.5f);
        fx = fminf(fmaxf(fx, 0.0f), (float)(n_in - 1));
        const int idx = (int)fx;
        const float l = -1.0f + r_in + 2.0f * r_in * (float)idx;
        dvals[v * n_out + i] = (c - l) * (float)n_in;
        ivals[v * n_out + i] = idx;
    }
    float x = fminf(fmaxf(((c + 1.0f) * (float)n_in - 1.0f) * 0.5f, 0.0f), (float)(n_in - 1));
    const float x0 = floorf(x);
    fr[i] = x - x0;
    const int i0 = (int)x0;
    l0[i] = i0;
    l1[i] = min(i0 + 1, n_in - 1);
}

// ---------------- kernel A: flat setup (113 blocks, shallow coalesced duties) ----------------
// b in [0,64)   : W1fP pack (one B-fragment per thread, direct from global)
// b in [64,96)  : fc1P pack
// b in [96,112) : B1 + ACO fold (16 channels per block, 16-lane strided reduce)
// b == 112      : dtype flag + axis tables + sc-weight fold + fc1_b/fc2 staging
__global__ __launch_bounds__(256)
void k_setup(const void* __restrict__ feat,
             const void* __restrict__ dw1_w, const void* __restrict__ dw1_b,
             const void* __restrict__ pw1_w, const void* __restrict__ pw1_b,
             const void* __restrict__ fc1_w, const void* __restrict__ fc1_b,
             const void* __restrict__ fc2_w, const void* __restrict__ fc2_b,
             const void* __restrict__ sc_dw_w, const void* __restrict__ sc_dw_b,
             const void* __restrict__ sc_pw_w, const void* __restrict__ sc_pw_b,
             bf16* __restrict__ fc1P, bf16* __restrict__ W1fP,
             float* __restrict__ F, int* __restrict__ I) {
    const int tid = threadIdx.x;
    const int b = blockIdx.x;
    __shared__ int sflag;
    // per-block dtype detection (wave-0 ballot): even halfwords of fp32 data
    // are mantissa junk (~15% in bf16-exponent window); of bf16 data ~100%.
    if (tid < 64) {
        const unsigned short* u = (const unsigned short*)feat;
        const unsigned e = (u[2 * tid] >> 7) & 0xFFu;
        const unsigned long long m = __ballot(e >= 0x68u && e <= 0x8Eu);
        if (tid == 0) sflag = (__popcll(m) < 32) ? 1 : 0;
    }
    __syncthreads();
    const int f32 = sflag;

    if (b < 64) {
        // ---- W1fP pack: g in [0,16384) ----
        const int g = b * 256 + tid;
        const int kc = g >> 10, nt = (g >> 6) & 15, wl = g & 63;
        const int n = nt * 16 + (wl & 15);
        const int K0 = kc * 32 + (wl >> 4) * 8;
        bf16 v[8];
        #pragma unroll
        for (int jj = 0; jj < 8; ++jj) {
            const int ch = 24 + K0 + jj;
            v[jj] = f2b(ldin(pw1_w, n * 539 + ch, f32) * ldin(dw1_w, ch, f32));
        }
        *(short8x*)&W1fP[(size_t)g * 8] = *(short8x*)v;
        return;
    }
    if (b < 96) {
        // ---- fc1P pack: g in [0,8192) ----
        const int g = (b - 64) * 256 + tid;
        const int kc = g >> 10, nt = (g >> 6) & 15, wl = g & 63;
        const int n = nt * 16 + (wl & 15);
        const int K0 = kc * 32 + (wl >> 4) * 8;
        bf16 v[8];
        #pragma unroll
        for (int jj = 0; jj < 8; ++jj) v[jj] = f2b(ldin(fc1_w, n * 256 + K0 + jj, f32));
        *(short8x*)&fc1P[(size_t)g * 8] = *(short8x*)v;
        return;
    }
    if (b < 112) {
        // ---- B1 + ACO fold: channels n = (b-96)*16 + r ----
        const int r = tid >> 4, part = tid & 15;
        const int n = (b - 96) * 16 + r;
        float s = 0.f;
        for (int ch = part; ch < 539; ch += 16)
            s += ldin(pw1_w, n * 539 + ch, f32) * ldin(dw1_b, ch, f32);
        #pragma unroll
        for (int m = 1; m <= 8; m <<= 1) s += __shfl_xor(s, m, 64);
        if (part == 0) {
            float bacc = ldin(pw1_b, n, f32) + s;
            #pragma unroll
            for (int ch = 536; ch < 539; ++ch)
                bacc += 2.0f * ldin(pw1_w, n * 539 + ch, f32) * ldin(dw1_w, ch, f32);
            F[F_B1 + n] = bacc;
            float A[6] = {0.f, 0.f, 0.f, 0.f, 0.f, 0.f};
            #pragma unroll
            for (int k = 0; k < 8; ++k) {
                A[(k >> 2)]           += ldin(pw1_w, n*539 + 3*k + 0, f32) * ldin(dw1_w, 3*k + 0, f32);
                A[2 + ((k >> 1) & 1)] += ldin(pw1_w, n*539 + 3*k + 1, f32) * ldin(dw1_w, 3*k + 1, f32);
                A[4 + (k & 1)]        += ldin(pw1_w, n*539 + 3*k + 2, f32) * ldin(dw1_w, 3*k + 2, f32);
            }
            #pragma unroll
            for (int i = 0; i < 6; ++i) F[F_ACO + i * 256 + n] = A[i];
        }
        return;
    }
    // ---- block 112: flag + tables + small staging + sc-weight fold ----
    if (tid == 0) I[I_FLAG] = f32;
    F[F_FC1B + tid] = ldin(fc1_b, tid, f32);
    for (int r = tid; r < 768; r += 256) F[F_FC2W + r] = ldin(fc2_w, r, f32);
    if (tid < 3) F[F_FC2B + tid] = ldin(fc2_b, tid, f32);
    if (tid < 192)
        F[F_SCW + tid] = ldin(sc_pw_w, tid, f32) * ldin(sc_dw_w, tid & 63, f32);
    if (tid < 3) {
        float sb = ldin(sc_pw_b, tid, f32);
        for (int c = 0; c < 64; ++c)
            sb += ldin(sc_pw_w, tid * 64 + c, f32) * ldin(sc_dw_b, c, f32);
        F[F_SCB + tid] = sb;
    }
    if (tid < TO) axis_tables(tid, TO, TI, F + F_DT, I + I_IT, I + I_LT0, I + I_LT1, F + F_FT);
    if (tid < HO) axis_tables(tid, HO, HI, F + F_DH, I + I_IH, I + I_LH0, I + I_LH1, F + F_FH);
    if (tid < WO) axis_tables(tid, WO, WI, F + F_DW, I + I_IW, I + I_LW0, I + I_LW1, F + F_FW);
}

// ---------------- kernel B: MFMA corner projections P + shortcut sc ----------------
// grid (300 pos-tiles, 8 corners). Per block: M=32 positions, N=256, K=64.
__global__ __launch_bounds__(256)
void k_corner(const void* __restrict__ feat, float* __restrict__ F,
              const int* __restrict__ I, const bf16* __restrict__ W1fP,
              bf16* __restrict__ P) {
    const int tid = threadIdx.x;
    const int pt = blockIdx.x, k = blockIdx.y;
    const int pos0 = pt * 32;
    const int f32 = I[I_FLAG];

    __shared__ __align__(16) short ft[32 * FT_S];   // feat tile transposed [p][c] bf16
    __shared__ __align__(16) short zt[32 * ZPAD];   // P tile [p][o] bf16

    // stage feat tile (transpose [c][pos] -> [p][c]); bf16 conversion lossless
    {
        const int p = tid & 31, c0 = tid >> 5;   // c0 in 0..7
        #pragma unroll
        for (int cc = 0; cc < 8; ++cc) {
            const int c = c0 * 8 + cc;
            ft[p * FT_S + c] = bbits(ldin(feat, c * NIN + pos0 + p, f32));
        }
    }
    __syncthreads();

    // MFMA: 2 M-tiles x 4 N-tiles x 2 K-chunks per wave
    const int wl = tid & 63, w = tid >> 6;
    const int col = wl & 15, quad = wl >> 4;
    f32x4 acc[2][4] = { { {0,0,0,0},{0,0,0,0},{0,0,0,0},{0,0,0,0} },
                        { {0,0,0,0},{0,0,0,0},{0,0,0,0},{0,0,0,0} } };
    const short8x* bp = (const short8x*)W1fP;
    #pragma unroll
    for (int kc = 0; kc < 2; ++kc) {
        const short8x a0 = *(const short8x*)&ft[col * FT_S + kc * 32 + quad * 8];
        const short8x a1 = *(const short8x*)&ft[(col + 16) * FT_S + kc * 32 + quad * 8];
        #pragma unroll
        for (int nt = 0; nt < 4; ++nt) {
            const short8x bb = bp[((k * 2 + kc) * 16 + (w * 4 + nt)) * 64 + wl];
            acc[0][nt] = __builtin_amdgcn_mfma_f32_16x16x32_bf16(a0, bb, acc[0][nt], 0, 0, 0);
            acc[1][nt] = __builtin_amdgcn_mfma_f32_16x16x32_bf16(a1, bb, acc[1][nt], 0, 0, 0);
        }
    }

    // shortcut (only corner-0 blocks): sc[j][pos] from the staged tile
    if (k == 0 && tid < 96) {
        const int j = tid >> 5, p = tid & 31;
        float s = F[F_SCB + j];
        for (int c = 0; c < 64; ++c)
            s += bu2f((unsigned short)ft[p * FT_S + c]) * F[F_SCW + j * 64 + c];
        F[F_SC + j * NIN + pos0 + p] = s;
    }

    // write accumulators to LDS tile (D layout: m=quad*4+r, n=w*64+nt*16+col)
    #pragma unroll
    for (int mt = 0; mt < 2; ++mt)
        #pragma unroll
        for (int nt = 0; nt < 4; ++nt) {
            const int n = w * 64 + nt * 16 + col;
            #pragma unroll
            for (int r = 0; r < 4; ++r)
                zt[(mt * 16 + quad * 4 + r) * ZPAD + n] = bbits(acc[mt][nt][r]);
        }
    __syncthreads();

    // coalesced store: 32 rows x 512B contiguous per row
    #pragma unroll
    for (int q = 0; q < 4; ++q) {
        const int i = q * 256 + tid;            // 0..1023 chunks of 8 bf16
        const int p = i >> 5, c8 = i & 31;
        const short8x v = *(const short8x*)&zt[p * ZPAD + c8 * 8];
        *(short8x*)(P + ((size_t)(k * NIN + pos0 + p)) * 256 + c8 * 8) = v;
    }
}

// ---------------- kernel C: main fused MLP (MFMA fc1, in-register fc2) ----------------
__global__ __launch_bounds__(256)
void k_main(const bf16* __restrict__ P, const bf16* __restrict__ fc1P,
            const float* __restrict__ F, const int* __restrict__ I,
            void* __restrict__ outv) {
    const int tid = threadIdx.x;
    const int pos0 = blockIdx.x * MPOS;
    const int f32 = I[I_FLAG];

    __shared__ __align__(16) short zsh[MPOS * ZPAD];  // z bf16, [p][o]
    __shared__ float redc[MPOS * 4 * 3];              // fc2 per-wave partials [p][w][jj]
    __shared__ int   sh_ipos[MPOS][8];
    __shared__ float sh_wk[MPOS][8];
    __shared__ float sh_dv[MPOS][6];
    __shared__ float sh_g[3][MPOS];

    // ---- stage 1: per-position scalars (threads 0..31) ----
    if (tid < MPOS) {
        const int p = tid;
        const int pos = pos0 + p;
        const int t = pos / (HO * WO);
        const int rem = pos - t * (HO * WO);
        const int h = rem / WO;
        const int w = rem - h * WO;
        const int   iTa[2] = { I[I_IT + t], I[I_IT + TO + t] };
        const float dTv[2] = { F[F_DT + t], F[F_DT + TO + t] };
        const int   iHa[2] = { I[I_IH + h], I[I_IH + HO + h] };
        const float dHv[2] = { F[F_DH + h], F[F_DH + HO + h] };
        const int   iWa[2] = { I[I_IW + w], I[I_IW + WO + w] };
        const float dWv[2] = { F[F_DW + w], F[F_DW + WO + w] };
        sh_dv[p][0] = dTv[0]; sh_dv[p][1] = dTv[1];
        sh_dv[p][2] = dHv[0]; sh_dv[p][3] = dHv[1];
        sh_dv[p][4] = dWv[0]; sh_dv[p][5] = dWv[1];
        const float aT[2] = { fabsf(dTv[0]), fabsf(dTv[1]) };
        const float aH[2] = { fabsf(dHv[0]), fabsf(dHv[1]) };
        const float aW[2] = { fabsf(dWv[0]), fabsf(dWv[1]) };
        const float tot = (aT[0] + aT[1]) * (aH[0] + aH[1]) * (aW[0] + aW[1]) + 8e-9f;
        #pragma unroll
        for (int k = 0; k < 8; ++k) {
            const int at = k >> 2, ah = (k >> 1) & 1, aw = k & 1;
            sh_wk[p][k] = (aT[1 - at] * aH[1 - ah] * aW[1 - aw] + 1e-9f) / tot;
            sh_ipos[p][k] = iTa[at] * (HI * WI) + iHa[ah] * WI + iWa[aw];
        }
        // trilinear shortcut g
        const int a0 = I[I_LT0 + t], a1 = I[I_LT1 + t];
        const int bh0 = I[I_LH0 + h], bh1 = I[I_LH1 + h];
        const int c0 = I[I_LW0 + w], c1 = I[I_LW1 + w];
        const float fT = F[F_FT + t], fH = F[F_FH + h], fW = F[F_FW + w];
        #pragma unroll
        for (int jj = 0; jj < 3; ++jj) {
            const float* Sj = F + F_SC + jj * NIN;
            const int i0 = a0 * (HI * WI), i1 = a1 * (HI * WI);
            const float v000 = Sj[i0 + bh0 * WI + c0], v001 = Sj[i0 + bh0 * WI + c1];
            const float v010 = Sj[i0 + bh1 * WI + c0], v011 = Sj[i0 + bh1 * WI + c1];
            const float v100 = Sj[i1 + bh0 * WI + c0], v101 = Sj[i1 + bh0 * WI + c1];
            const float v110 = Sj[i1 + bh1 * WI + c0], v111 = Sj[i1 + bh1 * WI + c1];
            const float u00 = v000 * (1.f - fT) + v100 * fT;
            const float u01 = v001 * (1.f - fT) + v101 * fT;
            const float u10 = v010 * (1.f - fT) + v110 * fT;
            const float u11 = v011 * (1.f - fT) + v111 * fT;
            const float q0 = u00 * (1.f - fH) + u10 * fH;
            const float q1 = u01 * (1.f - fH) + u11 * fH;
            sh_g[jj][p] = q0 * (1.f - fW) + q1 * fW;
        }
    }
    __syncthreads();

    // ---- stage 2: z[p][o] = b1eff + Acoef·dv + sum_k wk * P[k][ipos][o] ----
    // thread = (og, pg): 8 consecutive channels o8=og*8, 4 positions p=pg*4+pp
    {
        const int og = tid & 31, pg = tid >> 5;
        const int o8 = og * 8;
        const float4 bz0 = *(const float4*)&F[F_B1 + o8];
        const float4 bz1 = *(const float4*)&F[F_B1 + o8 + 4];
        float4 Ac0[6], Ac1[6];
        #pragma unroll
        for (int i = 0; i < 6; ++i) {
            Ac0[i] = *(const float4*)&F[F_ACO + i * 256 + o8];
            Ac1[i] = *(const float4*)&F[F_ACO + i * 256 + o8 + 4];
        }
        #pragma unroll
        for (int pp = 0; pp < 4; ++pp) {
            const int p = pg * 4 + pp;
            float a[8] = { bz0.x, bz0.y, bz0.z, bz0.w, bz1.x, bz1.y, bz1.z, bz1.w };
            #pragma unroll
            for (int i = 0; i < 6; ++i) {
                const float dv = sh_dv[p][i];
                a[0] += Ac0[i].x * dv; a[1] += Ac0[i].y * dv;
                a[2] += Ac0[i].z * dv; a[3] += Ac0[i].w * dv;
                a[4] += Ac1[i].x * dv; a[5] += Ac1[i].y * dv;
                a[6] += Ac1[i].z * dv; a[7] += Ac1[i].w * dv;
            }
            #pragma unroll
            for (int k = 0; k < 8; ++k) {
                const float wk = sh_wk[p][k];
                const ushort8x u = *(const ushort8x*)(P + ((size_t)(k * NIN + sh_ipos[p][k]) * 256 + o8));
                #pragma unroll
                for (int j = 0; j < 8; ++j) a[j] += wk * bu2f(u[j]);
            }
            short zz[8];
            #pragma unroll
            for (int j = 0; j < 8; ++j) zz[j] = bbits(a[j]);
            *(short8x*)&zsh[p * ZPAD + o8] = *(short8x*)zz;
        }
    }
    __syncthreads();

    // ---- stage 3: fc1 via MFMA (2 M-tiles) + gelu + fc2 partials in-register ----
    {
        const int wl = tid & 63, w = tid >> 6;
        const int col = wl & 15, quad = wl >> 4;
        f32x4 acc0[4] = { {0,0,0,0}, {0,0,0,0}, {0,0,0,0}, {0,0,0,0} };
        f32x4 acc1[4] = { {0,0,0,0}, {0,0,0,0}, {0,0,0,0}, {0,0,0,0} };
        const short8x* bp = (const short8x*)fc1P;
        #pragma unroll
        for (int kc = 0; kc < 8; ++kc) {
            const short8x a0 = *(const short8x*)&zsh[col * ZPAD + kc * 32 + quad * 8];
            const short8x a1 = *(const short8x*)&zsh[(col + 16) * ZPAD + kc * 32 + quad * 8];
            #pragma unroll
            for (int nt = 0; nt < 4; ++nt) {
                const short8x b = bp[(kc * 16 + w * 4 + nt) * 64 + wl];
                acc0[nt] = __builtin_amdgcn_mfma_f32_16x16x32_bf16(a0, b, acc0[nt], 0, 0, 0);
                acc1[nt] = __builtin_amdgcn_mfma_f32_16x16x32_bf16(a1, b, acc1[nt], 0, 0, 0);
            }
        }
        // gelu + fc2 partial sums; D layout: m = quad*4+r, n = w*64+nt*16+col
        float part[2][3][4];
        #pragma unroll
        for (int mt = 0; mt < 2; ++mt)
            #pragma unroll
            for (int jj = 0; jj < 3; ++jj)
                #pragma unroll
                for (int r = 0; r < 4; ++r) part[mt][jj][r] = 0.f;
        #pragma unroll
        for (int nt = 0; nt < 4; ++nt) {
            const int j = w * 64 + nt * 16 + col;
            const float fb = F[F_FC1B + j];
            const float w0 = F[F_FC2W + j];
            const float w1 = F[F_FC2W + 256 + j];
            const float w2 = F[F_FC2W + 512 + j];
            #pragma unroll
            for (int r = 0; r < 4; ++r) {
                float hh = gelu_f(acc0[nt][r] + fb);
                part[0][0][r] += w0 * hh; part[0][1][r] += w1 * hh; part[0][2][r] += w2 * hh;
                hh = gelu_f(acc1[nt][r] + fb);
                part[1][0][r] += w0 * hh; part[1][1][r] += w1 * hh; part[1][2][r] += w2 * hh;
            }
        }
        // butterfly-reduce over the 16 col-lanes
        #pragma unroll
        for (int m = 1; m <= 8; m <<= 1)
            #pragma unroll
            for (int mt = 0; mt < 2; ++mt)
                #pragma unroll
                for (int jj = 0; jj < 3; ++jj)
                    #pragma unroll
                    for (int r = 0; r < 4; ++r)
                        part[mt][jj][r] += __shfl_xor(part[mt][jj][r], m, 64);
        if (col == 0) {
            #pragma unroll
            for (int mt = 0; mt < 2; ++mt)
                #pragma unroll
                for (int jj = 0; jj < 3; ++jj)
                    #pragma unroll
                    for (int r = 0; r < 4; ++r) {
                        const int p = mt * 16 + quad * 4 + r;
                        redc[(p * 4 + w) * 3 + jj] = part[mt][jj][r];
                    }
        }
    }
    __syncthreads();

    // ---- stage 4: combine 4 wave-partials + shortcut + store ----
    if (tid < 96) {
        const int p = tid / 3, jj = tid - 3 * p;
        float a = F[F_FC2B + jj] + sh_g[jj][p];
        #pragma unroll
        for (int w = 0; w < 4; ++w) a += redc[(p * 4 + w) * 3 + jj];
        const int oidx = jj * NOUT + pos0 + p;
        if (f32) ((float*)outv)[oidx] = a;
        else     ((bf16*)outv)[oidx] = f2b(a);
    }
}

extern "C" void kernel_launch(void* const* d_in, const int* in_sizes, int n_in,
                              void* d_out, int out_size, void* d_ws, size_t ws_size,
                              hipStream_t stream) {
    const void* feat    = d_in[0];
    const void* dw1_w   = d_in[1];
    const void* dw1_b   = d_in[2];
    const void* pw1_w   = d_in[3];
    const void* pw1_b   = d_in[4];
    const void* fc1_w   = d_in[5];
    const void* fc1_b   = d_in[6];
    const void* fc2_w   = d_in[7];
    const void* fc2_b   = d_in[8];
    const void* sc_dw_w = d_in[9];
    const void* sc_dw_b = d_in[10];
    const void* sc_pw_w = d_in[11];
    const void* sc_pw_b = d_in[12];

    const size_t P_BYTES    = (size_t)8 * NIN * 256 * 2;   // 39,321,600
    const size_t FC1P_BYTES = (size_t)256 * 256 * 2;       // 131,072
    const size_t W1FP_BYTES = (size_t)512 * 256 * 2;       // 262,144
    bf16*  P    = (bf16*)d_ws;
    bf16*  fc1P = (bf16*)((char*)d_ws + P_BYTES);
    bf16*  W1fP = (bf16*)((char*)d_ws + P_BYTES + FC1P_BYTES);
    float* F    = (float*)((char*)d_ws + P_BYTES + FC1P_BYTES + W1FP_BYTES);
    int*   I    = (int*)(F + F_END);
    // total ws need ~39.9 MB

    k_setup<<<113, 256, 0, stream>>>(feat, dw1_w, dw1_b, pw1_w, pw1_b, fc1_w, fc1_b,
                                     fc2_w, fc2_b, sc_dw_w, sc_dw_b, sc_pw_w, sc_pw_b,
                                     fc1P, W1fP, F, I);
    k_corner<<<dim3(NIN / 32, 8), 256, 0, stream>>>(feat, F, I, W1fP, P);
    k_main<<<NOUT / MPOS, 256, 0, stream>>>(P, fc1P, F, I, (void*)d_out);
}